// Round 3
// baseline (242.442 us; speedup 1.0000x reference)
//
#include <hip/hip_runtime.h>
#include <hip/hip_fp16.h>
#include <stdint.h>

// BATCH=4096, LENGTH=128, FEAT=4, RANK=64, 126 mid sites.
#define NSITES 126
#define XPITCH 516

typedef _Float16 half8_t  __attribute__((ext_vector_type(8)));
typedef float    float4_t __attribute__((ext_vector_type(4)));

// Column permutation: tile (u,i) puts m-row m at G-column 64i + rho(u,m).
// Chosen so D-regs after i-combine ARE the next site's B-frag elements.
__device__ __forceinline__ constexpr int rho_map(int u, int m) {
    return 32*(u>>1) + 8*(m>>2) + 4*(u&1) + (m&3);
}

// ---------------------------------------------------------------------------
// Repack mid_cores fp32 [126][64][256] -> fp16 A-fragments (G in the A slot):
// frag fi = kk*16 + u*4 + i, lane(q,c): element j = G[l=32kk+8q+j][64i+rho(u,c)]
// ---------------------------------------------------------------------------
__global__ __launch_bounds__(256) void repack_g(const float* __restrict__ mid,
                                                _Float16* __restrict__ gt) {
    __shared__ float lds[64 * 260];
    const int s = blockIdx.x, t = threadIdx.x;
    const float* src = mid + (size_t)s * 16384;
#pragma unroll
    for (int k = 0; k < 16; ++k) {
        const int f4 = t + 256 * k;
        const int l = f4 >> 6, n0 = (f4 & 63) * 4;
        *(float4_t*)&lds[l * 260 + n0] = *(const float4_t*)&src[f4 * 4];
    }
    __syncthreads();
    half8_t* dst = (half8_t*)gt + (size_t)s * 2048;
#pragma unroll
    for (int m = 0; m < 8; ++m) {
        const int F = t + 256 * m;
        const int lane = F & 63, fi = F >> 6;
        const int kk = fi >> 4, u = (fi >> 2) & 3, i = fi & 3;
        const int q = lane >> 4, c = lane & 15;
        const int n = 64 * i + rho_map(u, c);
        half8_t o;
#pragma unroll
        for (int j = 0; j < 8; ++j)
            o[j] = (_Float16)lds[(32 * kk + 8 * q + j) * 260 + n];
        dst[F] = o;
    }
}

// ---------------------------------------------------------------------------
// Single-wave tensor-train chain: 128 blocks x 64 threads; wave owns 32
// batches (two n=16 groups g sharing G A-frags in registers, double-buffered
// from global). No barriers, no cross-lane exchange in the site loop.
// ---------------------------------------------------------------------------
__global__ __launch_bounds__(64, 1) void tt_chain(
    const float* __restrict__ x,      // [4096][128][4]
    const float* __restrict__ first,  // [4][64]
    const float* __restrict__ last,   // [64][4]
    const _Float16* __restrict__ gt,  // frag-ordered fp16, 2048 half8/site
    float* __restrict__ out) {        // [4096]

    __shared__ float xbuf[32 * XPITCH];
    const int lane = threadIdx.x;
    const int q = lane >> 4, c = lane & 15;
    const int b0 = blockIdx.x * 32;

    // stage x rows b0..b0+31 (64 KB contiguous), coalesced
    {
        const float4_t* src = (const float4_t*)(x + (size_t)b0 * 512);
#pragma unroll
        for (int k = 0; k < 64; ++k) {
            const int f4 = lane + 64 * k;
            const int row = f4 >> 7, col4 = f4 & 127;
            *(float4_t*)&xbuf[row * XPITCH + col4 * 4] = src[f4];
        }
    }
    __syncthreads();

    // register G pipeline (2 x 32 frags = 256 VGPR)
    half8_t FA[32], FB[32];
    auto LOAD = [&](int s, half8_t* F) {
        const half8_t* p = (const half8_t*)gt + (size_t)s * 2048 + lane;
#pragma unroll
        for (int fi = 0; fi < 32; ++fi) F[fi] = p[fi * 64];
    };
    LOAD(0, FA);
    LOAD(1, FB);

    // v0 B-frags: bf[g][kk] element j = v0[b0+16g+c][l=32kk+8q+j]
    half8_t bf[2][2];
    {
        float4_t xs0[2];
        xs0[0] = *(const float4_t*)&xbuf[c * XPITCH];
        xs0[1] = *(const float4_t*)&xbuf[(c + 16) * XPITCH];
#pragma unroll
        for (int kk = 0; kk < 2; ++kk) {
            float4_t vlo[2] = {{0,0,0,0},{0,0,0,0}};
            float4_t vhi[2] = {{0,0,0,0},{0,0,0,0}};
#pragma unroll
            for (int i = 0; i < 4; ++i) {
                const float4_t flo = *(const float4_t*)&first[i*64 + 32*kk + 8*q];
                const float4_t fhi = *(const float4_t*)&first[i*64 + 32*kk + 8*q + 4];
#pragma unroll
                for (int g = 0; g < 2; ++g) {
                    const float xv = xs0[g][i];
                    const float4_t xv4 = {xv, xv, xv, xv};
                    vlo[g] = __builtin_elementwise_fma(flo, xv4, vlo[g]);
                    vhi[g] = __builtin_elementwise_fma(fhi, xv4, vhi[g]);
                }
            }
#pragma unroll
            for (int g = 0; g < 2; ++g) {
                half8_t nb;
#pragma unroll
                for (int jj = 0; jj < 4; ++jj) {
                    nb[jj]     = (_Float16)vlo[g][jj];   // RTN cast (RTZ pack
                    nb[4 + jj] = (_Float16)vhi[g][jj];   // biases -6% over chain)
                }
                bf[g][kk] = nb;
            }
        }
    }

    float4_t comb[2][4];   // comb[g][u][jj] = v_{s+1}[b0+16g+c][rho(u,4q+jj)]
    int e0 = 0, e1 = 0;    // per-batch power-of-2 renorm exponents

    auto STEP = [&](int s, half8_t* F) {
        float4_t xs[2];
        xs[0] = *(const float4_t*)&xbuf[c * XPITCH + 4 * (s + 1)];
        xs[1] = *(const float4_t*)&xbuf[(c + 16) * XPITCH + 4 * (s + 1)];
#pragma unroll
        for (int g = 0; g < 2; ++g)
#pragma unroll
            for (int u = 0; u < 4; ++u) {
                float4_t cc = {0, 0, 0, 0};
#pragma unroll
                for (int i = 0; i < 4; ++i) {
                    float4_t z = {0, 0, 0, 0};
                    z = __builtin_amdgcn_mfma_f32_16x16x32_f16(F[u*4 + i],      bf[g][0], z, 0, 0, 0);
                    z = __builtin_amdgcn_mfma_f32_16x16x32_f16(F[16 + u*4 + i], bf[g][1], z, 0, 0, 0);
                    const float xv = xs[g][i];
                    const float4_t xv4 = {xv, xv, xv, xv};
                    cc = __builtin_elementwise_fma(z, xv4, cc);
                }
                comb[g][u] = cc;
            }

        // wave-local per-batch renorm every 8 sites (keeps fp16 cast in range)
        if (((s + 1) & 7) == 0) {
            float m0 = 0.f, m1 = 0.f;
#pragma unroll
            for (int u = 0; u < 4; ++u)
#pragma unroll
                for (int jj = 0; jj < 4; ++jj) {
                    m0 = fmaxf(m0, fabsf(comb[0][u][jj]));
                    m1 = fmaxf(m1, fabsf(comb[1][u][jj]));
                }
            m0 = fmaxf(m0, __shfl_xor(m0, 16)); m0 = fmaxf(m0, __shfl_xor(m0, 32));
            m1 = fmaxf(m1, __shfl_xor(m1, 16)); m1 = fmaxf(m1, __shfl_xor(m1, 32));
            int ee0 = 0, ee1 = 0;
            if (m0 > 0.f) frexpf(m0, &ee0);
            if (m1 > 0.f) frexpf(m1, &ee1);
            const float sc0 = ldexpf(1.f, -ee0), sc1 = ldexpf(1.f, -ee1);
#pragma unroll
            for (int u = 0; u < 4; ++u) {
                comb[0][u] *= sc0;
                comb[1][u] *= sc1;
            }
            e0 += ee0; e1 += ee1;
        }

        // cast comb -> next B-frags (layouts self-match via rho: no shuffle)
#pragma unroll
        for (int g = 0; g < 2; ++g) {
            half8_t n0, n1;
#pragma unroll
            for (int jj = 0; jj < 4; ++jj) {
                n0[jj]     = (_Float16)comb[g][0][jj];
                n0[4 + jj] = (_Float16)comb[g][1][jj];
                n1[jj]     = (_Float16)comb[g][2][jj];
                n1[4 + jj] = (_Float16)comb[g][3][jj];
            }
            bf[g][0] = n0;
            bf[g][1] = n1;
        }
    };

    for (int s = 0; s < NSITES; s += 2) {
        STEP(s, FA);
        LOAD(s + 2 <= NSITES - 1 ? s + 2 : NSITES - 1, FA);
        STEP(s + 1, FB);
        LOAD(s + 3 <= NSITES - 1 ? s + 3 : NSITES - 1, FB);
    }

    // epilogue: out[b] = 2^e * sum_r v126[b][r] * (sum_i last[r][i] x[b][127][i])
    {
        const float4_t xl0 = *(const float4_t*)&xbuf[c * XPITCH + 508];
        const float4_t xl1 = *(const float4_t*)&xbuf[(c + 16) * XPITCH + 508];
        float dot0 = 0.f, dot1 = 0.f;
#pragma unroll
        for (int u = 0; u < 4; ++u)
#pragma unroll
            for (int jj = 0; jj < 4; ++jj) {
                const int r = rho_map(u, 4 * q + jj);
                const float4_t lr = *(const float4_t*)&last[r * 4];
                const float lv0 = lr[0]*xl0[0] + lr[1]*xl0[1] + lr[2]*xl0[2] + lr[3]*xl0[3];
                const float lv1 = lr[0]*xl1[0] + lr[1]*xl1[1] + lr[2]*xl1[2] + lr[3]*xl1[3];
                dot0 += comb[0][u][jj] * lv0;
                dot1 += comb[1][u][jj] * lv1;
            }
        dot0 += __shfl_xor(dot0, 16); dot0 += __shfl_xor(dot0, 32);
        dot1 += __shfl_xor(dot1, 16); dot1 += __shfl_xor(dot1, 32);
        if (lane < 16)      out[b0 + lane] = ldexpf(dot0, e0);
        else if (lane < 32) out[b0 + lane] = ldexpf(dot1, e1);
    }
}

extern "C" void kernel_launch(void* const* d_in, const int* in_sizes, int n_in,
                              void* d_out, int out_size, void* d_ws, size_t ws_size,
                              hipStream_t stream) {
    (void)in_sizes; (void)n_in; (void)out_size; (void)ws_size;
    const float* x     = (const float*)d_in[0];
    const float* first = (const float*)d_in[1];
    const float* mid   = (const float*)d_in[2];
    const float* last  = (const float*)d_in[3];
    float* out = (float*)d_out;
    _Float16* gt = (_Float16*)d_ws;   // 126*2048*16 B = 4,128,768 B

    repack_g<<<126, 256, 0, stream>>>(mid, gt);
    tt_chain<<<128, 64, 0, stream>>>(x, first, last, gt, out);
}